// Round 1
// baseline (382.479 us; speedup 1.0000x reference)
//
#include <hip/hip_runtime.h>
#include <hip/hip_bf16.h>
#include <hip/hip_fp16.h>

#define B_    2
#define SQ_   2048
#define SK_   2048
#define HQ_   32
#define HKV_  8
#define D_    128
#define W_    512
#define QBLK  16
#define KVBLK 32
#define SPITCH 552   // fp16 elems/row: max span 544, padded; 552*2=1104B keeps rows 16B-aligned

typedef short    s16x8 __attribute__((ext_vector_type(8)));
typedef float    f32x4 __attribute__((ext_vector_type(4)));
typedef _Float16 f16x8 __attribute__((ext_vector_type(8)));

static __device__ __forceinline__ short bf16b(float x){
    __hip_bfloat16 h = __float2bfloat16(x);
    return *reinterpret_cast<short*>(&h);
}

// ---- prep 1: cast K fp32 -> bf16 (same layout [b][sk][hkv][d]) ----
__global__ void cast_k_bf16(const float* __restrict__ k, short* __restrict__ kb){
    int idx = blockIdx.x * 256 + threadIdx.x;          // each handles 8 elems
    const float4* src = reinterpret_cast<const float4*>(k) + (size_t)idx * 2;
    float4 a = src[0], b = src[1];
    s16x8 o;
    o[0]=bf16b(a.x); o[1]=bf16b(a.y); o[2]=bf16b(a.z); o[3]=bf16b(a.w);
    o[4]=bf16b(b.x); o[5]=bf16b(b.y); o[6]=bf16b(b.z); o[7]=bf16b(b.w);
    reinterpret_cast<s16x8*>(kb)[idx] = o;
}

// ---- prep 2: V fp32 [b][sk][hkv][d] -> VT bf16 [b][hkv][d][sk] ----
__global__ void transpose_v(const float* __restrict__ v, short* __restrict__ vt){
    __shared__ short tile[32][33];
    int s0 = blockIdx.x * 32, d0 = blockIdx.y * 32, bh = blockIdx.z;
    int b = bh >> 3, h = bh & 7;
    int tx = threadIdx.x & 31, ty = threadIdx.x >> 5;   // ty 0..7
    const float* base = v + ((size_t)b * SK_ + s0) * (HKV_ * D_) + h * D_ + d0;
    #pragma unroll
    for (int r = 0; r < 4; ++r){
        int s = ty * 4 + r;
        tile[s][tx] = bf16b(base[(size_t)s * (HKV_ * D_) + tx]);
    }
    __syncthreads();
    short* obase = vt + ((size_t)(b * HKV_ + h) * D_ + d0) * SK_ + s0;
    #pragma unroll
    for (int r = 0; r < 4; ++r){
        int dl = ty * 4 + r;
        obase[(size_t)dl * SK_ + tx] = tile[tx][dl];
    }
}

// ---- main: one wave per 16-row Q tile, two-pass (S window in LDS fp16) ----
__global__ __launch_bounds__(64)
void attn_kernel(const float* __restrict__ q, const short* __restrict__ kb,
                 const short* __restrict__ vt, float* __restrict__ out){
    __shared__ _Float16 Slds[QBLK][SPITCH];
    __shared__ float lm[QBLK], llv[QBLK];

    int bid = blockIdx.x;
    int qt = bid & 127;            // SQ_/QBLK
    int h  = (bid >> 7) & 31;
    int b  = bid >> 12;
    int qb = qt * QBLK;
    int hkv = h >> 2;

    int lane = threadIdx.x;
    int g = lane >> 4;             // 0..3
    int c = lane & 15;             // 0..15

    // Q fragments (A-frag): row=c (q), k = db*32 + g*8 + i ; fp32->bf16 inline, once
    s16x8 qf[4];
    {
        const float* qrow = q + (((size_t)b * SQ_ + qb + c) * HQ_ + h) * D_;
        #pragma unroll
        for (int db = 0; db < 4; ++db){
            const float4* p = reinterpret_cast<const float4*>(qrow + db * 32 + g * 8);
            float4 x = p[0], y = p[1];
            s16x8 f;
            f[0]=bf16b(x.x); f[1]=bf16b(x.y); f[2]=bf16b(x.z); f[3]=bf16b(x.w);
            f[4]=bf16b(y.x); f[5]=bf16b(y.y); f[6]=bf16b(y.z); f[7]=bf16b(y.w);
            qf[db] = f;
        }
    }

    int lo = qb - W_; if (lo < 0) lo = 0;
    int t0 = lo & ~(KVBLK - 1);
    int t1 = (qb + QBLK - 1) & ~(KVBLK - 1);

    float m[4], lsum[4];
    #pragma unroll
    for (int j = 0; j < 4; ++j){ m[j] = -1e30f; lsum[j] = 0.f; }

    const float scale_over_cap = 0.08838834764831845f / 30.0f;

    // ---------------- pass 1: QK^T, cap, mask, store S, online (m, l) ----------------
    for (int t = t0; t <= t1; t += KVBLK){
        #pragma unroll
        for (int hh = 0; hh < 2; ++hh){
            int kvc = t + hh * 16 + c;  // this lane's kv column
            const short* krow = kb + (((size_t)b * SK_ + kvc) * HKV_ + hkv) * D_;
            f32x4 acc = {0.f, 0.f, 0.f, 0.f};
            #pragma unroll
            for (int db = 0; db < 4; ++db){
                s16x8 kf = *reinterpret_cast<const s16x8*>(krow + db * 32 + g * 8);
                acc = __builtin_amdgcn_mfma_f32_16x16x32_bf16(qf[db], kf, acc, 0, 0, 0);
            }
            // acc[j] = S_raw[row = g*4+j][col = kvc]
            #pragma unroll
            for (int j = 0; j < 4; ++j){
                int qrow = qb + g * 4 + j;
                float x = acc[j] * scale_over_cap;
                float e = __expf(2.f * x);
                float s = 30.f * (e - 1.f) / (e + 1.f);      // CAP*tanh(logit*SCALE/CAP)
                bool ok = (kvc <= qrow) && (kvc >= qrow - W_);
                s = ok ? s : -65504.f;
                Slds[g * 4 + j][t - t0 + hh * 16 + c] = (_Float16)s;
                // row-wise online stats over the 16 lanes of this group
                float tm = s;
                #pragma unroll
                for (int off = 1; off < 16; off <<= 1)
                    tm = fmaxf(tm, __shfl_xor(tm, off));
                float mn = fmaxf(m[j], tm);
                float ex = __expf(s - mn);
                #pragma unroll
                for (int off = 1; off < 16; off <<= 1)
                    ex += __shfl_xor(ex, off);
                lsum[j] = lsum[j] * __expf(m[j] - mn) + ex;
                m[j] = mn;
            }
        }
    }

    if (c == 0){
        #pragma unroll
        for (int j = 0; j < 4; ++j){ lm[g * 4 + j] = m[j]; llv[g * 4 + j] = lsum[j]; }
    }
    __syncthreads();
    float mrow = lm[c];
    float rl = 1.02f / llv[c];

    // ---------------- pass 2: p' = clamp(1.02*exp(s-m)/l - 0.01, 0, 1); O += p'·V ----------------
    f32x4 o[8];
    #pragma unroll
    for (int dt = 0; dt < 8; ++dt) o[dt] = (f32x4){0.f, 0.f, 0.f, 0.f};

    const short* vbase = vt + (size_t)(b * HKV_ + hkv) * D_ * SK_;

    for (int t = t0; t <= t1; t += KVBLK){
        f16x8 sh = *reinterpret_cast<const f16x8*>(&Slds[c][t - t0 + g * 8]);
        s16x8 pf;
        #pragma unroll
        for (int i = 0; i < 8; ++i){
            float p = __expf((float)sh[i] - mrow) * rl - 0.01f;
            p = fminf(fmaxf(p, 0.f), 1.f);
            pf[i] = bf16b(p);
        }
        #pragma unroll
        for (int dt = 0; dt < 8; ++dt){
            s16x8 vf = *reinterpret_cast<const s16x8*>(vbase + (size_t)(dt * 16 + c) * SK_ + t + g * 8);
            o[dt] = __builtin_amdgcn_mfma_f32_16x16x32_bf16(pf, vf, o[dt], 0, 0, 0);
        }
    }

    // epilogue: D layout col=lane&15, row=(lane>>4)*4+j
    float* obase = out + (((size_t)b * SQ_ + qb) * HQ_ + h) * D_;
    #pragma unroll
    for (int dt = 0; dt < 8; ++dt){
        #pragma unroll
        for (int j = 0; j < 4; ++j){
            obase[(size_t)(g * 4 + j) * (HQ_ * D_) + dt * 16 + c] = o[dt][j];
        }
    }
}

extern "C" void kernel_launch(void* const* d_in, const int* in_sizes, int n_in,
                              void* d_out, int out_size, void* d_ws, size_t ws_size,
                              hipStream_t stream){
    const float* q = (const float*)d_in[0];
    const float* k = (const float*)d_in[1];
    const float* v = (const float*)d_in[2];
    float* out = (float*)d_out;

    short* kb  = (short*)d_ws;                 // 4,194,304 bf16 = 8 MiB
    short* vtp = (short*)d_ws + 4194304;       // 4,194,304 bf16 = 8 MiB  (needs 16 MiB ws)

    cast_k_bf16<<<2048, 256, 0, stream>>>(k, kb);
    transpose_v<<<dim3(SK_ / 32, D_ / 32, B_ * HKV_), 256, 0, stream>>>(v, vtp);
    attn_kernel<<<B_ * HQ_ * (SQ_ / QBLK), 64, 0, stream>>>(q, kb, vtp, out);
}

// Round 3
// 376.712 us; speedup vs baseline: 1.0153x; 1.0153x over previous
//
#include <hip/hip_runtime.h>
#include <hip/hip_bf16.h>

#define B_    2
#define SQ_   2048
#define SK_   2048
#define HQ_   32
#define HKV_  8
#define D_    128
#define W_    512
#define QBLK  16
#define KVBLK 32
#define SPITCH 552   // bf16 elems/row: span 544 + pad; 552*2=1104B keeps rows 16B-aligned, stride 276 words = 20 mod 32 banks

typedef short s16x8 __attribute__((ext_vector_type(8)));
typedef float f32x4 __attribute__((ext_vector_type(4)));

static __device__ __forceinline__ short bf16b(float x){
    __hip_bfloat16 h = __float2bfloat16(x);
    return *reinterpret_cast<short*>(&h);
}
static __device__ __forceinline__ float b2f(short u){
    return __uint_as_float(((unsigned int)(unsigned short)u) << 16);
}
static __device__ __forceinline__ float fexp2(float x){
    return __builtin_amdgcn_exp2f(x);
}

// ---- prep 1: cast K fp32 -> bf16 (same layout [b][sk][hkv][d]) ----
__global__ void cast_k_bf16(const float* __restrict__ k, short* __restrict__ kb){
    int idx = blockIdx.x * 256 + threadIdx.x;          // each handles 8 elems
    const float4* src = reinterpret_cast<const float4*>(k) + (size_t)idx * 2;
    float4 a = src[0], b = src[1];
    s16x8 o;
    o[0]=bf16b(a.x); o[1]=bf16b(a.y); o[2]=bf16b(a.z); o[3]=bf16b(a.w);
    o[4]=bf16b(b.x); o[5]=bf16b(b.y); o[6]=bf16b(b.z); o[7]=bf16b(b.w);
    reinterpret_cast<s16x8*>(kb)[idx] = o;
}

// ---- prep 2: V fp32 [b][sk][hkv][d] -> VT bf16 [b][hkv][d][sk] ----
// 64 s x 32 d tile; LDS pitch 66 shorts; output via 4x b32 LDS reads -> one 16B global store.
__global__ void transpose_v(const float* __restrict__ v, short* __restrict__ vt){
    __shared__ short tT[32][66];
    int s0 = blockIdx.x * 64, d0 = blockIdx.y * 32, bh = blockIdx.z;
    int b = bh >> 3, hv = bh & 7;
    int tid = threadIdx.x;
    int s = tid >> 2, dq = (tid & 3) * 8;
    const float* src = v + ((size_t)(b * SK_ + s0 + s) * HKV_ + hv) * D_ + d0 + dq;
    float4 x = *reinterpret_cast<const float4*>(src);
    float4 y = *reinterpret_cast<const float4*>(src + 4);
    tT[dq + 0][s] = bf16b(x.x); tT[dq + 1][s] = bf16b(x.y);
    tT[dq + 2][s] = bf16b(x.z); tT[dq + 3][s] = bf16b(x.w);
    tT[dq + 4][s] = bf16b(y.x); tT[dq + 5][s] = bf16b(y.y);
    tT[dq + 6][s] = bf16b(y.z); tT[dq + 7][s] = bf16b(y.w);
    __syncthreads();
    int d = tid >> 3, so = (tid & 7) * 8;
    union { unsigned int u[4]; s16x8 v8; } o;
    #pragma unroll
    for (int k2 = 0; k2 < 4; ++k2)
        o.u[k2] = *reinterpret_cast<const unsigned int*>(&tT[d][so + k2 * 2]);
    short* dst = vt + ((size_t)(b * HKV_ + hv) * D_ + d0 + d) * SK_ + s0 + so;
    *reinterpret_cast<s16x8*>(dst) = o.v8;
}

// ---- main: 4 waves/block = 4 q-heads of one KV group (shared K/V in L1/L2).
// Waves are fully independent (private LDS slices, shuffle-based row sums, no barriers).
// Fixed-max softmax: s = CAP*tanh(qk*SCALE/CAP) in (-30,30) -> u = exp(s) fits bf16.
// u = exp2(fma(rcp(exp2(acc*C1)+1), C2, C3)) fuses tanh+exp: 6 VALU ops, no cross-lane.
__global__ __launch_bounds__(256)
void attn_kernel(const float* __restrict__ q, const short* __restrict__ kb,
                 const short* __restrict__ vt, float* __restrict__ out){
    __shared__ short Su[4][QBLK][SPITCH];

    int bid = blockIdx.x;
    int qt  = bid & 127;             // SQ_/QBLK
    int hkv = (bid >> 7) & 7;
    int b   = bid >> 10;
    int w    = threadIdx.x >> 6;     // wave -> q-head within group
    int lane = threadIdx.x & 63;
    int h  = hkv * 4 + w;
    int qb = qt * QBLK;
    int g = lane >> 4, c = lane & 15;

    short (*S)[SPITCH] = Su[w];

    // Q fragments: A-frag row=c (q row qb+c), k = db*32 + g*8 + i
    s16x8 qf[4];
    {
        const float* qrow = q + (((size_t)b * SQ_ + qb + c) * HQ_ + h) * D_;
        #pragma unroll
        for (int db = 0; db < 4; ++db){
            const float4* p = reinterpret_cast<const float4*>(qrow + db * 32 + g * 8);
            float4 x = p[0], y = p[1];
            s16x8 f;
            f[0]=bf16b(x.x); f[1]=bf16b(x.y); f[2]=bf16b(x.z); f[3]=bf16b(x.w);
            f[4]=bf16b(y.x); f[5]=bf16b(y.y); f[6]=bf16b(y.z); f[7]=bf16b(y.w);
            qf[db] = f;
        }
    }

    int lo = qb - W_; if (lo < 0) lo = 0;
    int t0 = lo & ~(KVBLK - 1);
    int t1 = (qb + QBLK - 1) & ~(KVBLK - 1);

    // constants: SCALE = 1/sqrt(128), CAP = 30
    const float SCALE = 0.08838834764831845f;
    const float L2E   = 1.4426950408889634f;
    const float C1 = 2.0f * SCALE / 30.0f * L2E;   // e = exp2(acc*C1) = exp(2*logit/CAP)
    const float C2 = -60.0f * L2E;                 // u = exp2(C2*rcp(e+1) + C3) = exp(30*tanh(.))
    const float C3 =  30.0f * L2E;

    float ls[4] = {0.f, 0.f, 0.f, 0.f};

    // ---------------- pass 1: QK^T -> u = exp(s), store bf16, accumulate row sums ----------------
    for (int t = t0; t <= t1; t += KVBLK){
        #pragma unroll
        for (int hh = 0; hh < 2; ++hh){
            int kvc = t + hh * 16 + c;  // this lane's kv column
            const short* krow = kb + (((size_t)b * SK_ + kvc) * HKV_ + hkv) * D_;
            f32x4 acc = {0.f, 0.f, 0.f, 0.f};
            #pragma unroll
            for (int db = 0; db < 4; ++db){
                s16x8 kf = *reinterpret_cast<const s16x8*>(krow + db * 32 + g * 8);
                acc = __builtin_amdgcn_mfma_f32_16x16x32_bf16(qf[db], kf, acc, 0, 0, 0);
            }
            int col = t - t0 + hh * 16 + c;
            #pragma unroll
            for (int j = 0; j < 4; ++j){
                int qr = qb + g * 4 + j;
                float e = fexp2(acc[j] * C1);
                float r = __builtin_amdgcn_rcpf(e + 1.0f);
                float u = fexp2(fmaf(r, C2, C3));
                bool ok = (kvc <= qr) && (kvc >= qr - W_);
                u = ok ? u : 0.0f;
                ls[j] += u;
                S[g * 4 + j][col] = bf16b(u);
            }
        }
    }

    // row sums: xor-reduce over the 16 lanes of each g-group (4 shfl per j, once per wave)
    #pragma unroll
    for (int j = 0; j < 4; ++j){
        #pragma unroll
        for (int off = 1; off < 16; off <<= 1)
            ls[j] += __shfl_xor(ls[j], off);
    }
    // broadcast: row r=c lives in group g'=c>>2 slot j'=c&3
    int srcl = (c >> 2) << 4;
    float l0 = __shfl(ls[0], srcl), l1 = __shfl(ls[1], srcl);
    float l2 = __shfl(ls[2], srcl), l3 = __shfl(ls[3], srcl);
    float lrow = (c & 2) ? ((c & 1) ? l3 : l2) : ((c & 1) ? l1 : l0);
    float rl = 1.02f / lrow;

    // fence: LDS writes (cross-lane within wave) must land before pass-2 reads
    asm volatile("s_waitcnt lgkmcnt(0)" ::: "memory");

    // ---------------- pass 2: p' = clamp(u*rl - 0.01, 0, 1); O += p'·V ----------------
    f32x4 o[8];
    #pragma unroll
    for (int dt = 0; dt < 8; ++dt) o[dt] = (f32x4){0.f, 0.f, 0.f, 0.f};

    const short* vbase = vt + (size_t)(b * HKV_ + hkv) * D_ * SK_;

    for (int t = t0; t <= t1; t += KVBLK){
        s16x8 sh = *reinterpret_cast<const s16x8*>(&S[c][t - t0 + g * 8]);
        s16x8 pf;
        #pragma unroll
        for (int i = 0; i < 8; ++i){
            float p = fmaf(b2f(sh[i]), rl, -0.01f);
            p = fminf(fmaxf(p, 0.f), 1.f);
            pf[i] = bf16b(p);
        }
        #pragma unroll
        for (int dt = 0; dt < 8; ++dt){
            s16x8 vf = *reinterpret_cast<const s16x8*>(vbase + (size_t)(dt * 16 + c) * SK_ + t + g * 8);
            o[dt] = __builtin_amdgcn_mfma_f32_16x16x32_bf16(pf, vf, o[dt], 0, 0, 0);
        }
    }

    // epilogue: D layout col=lane&15 (=d sub-col), row=(lane>>4)*4+j (=q row)
    float* obase = out + (((size_t)b * SQ_ + qb) * HQ_ + h) * D_;
    #pragma unroll
    for (int dt = 0; dt < 8; ++dt){
        #pragma unroll
        for (int j = 0; j < 4; ++j){
            obase[(size_t)(g * 4 + j) * (HQ_ * D_) + dt * 16 + c] = o[dt][j];
        }
    }
}

extern "C" void kernel_launch(void* const* d_in, const int* in_sizes, int n_in,
                              void* d_out, int out_size, void* d_ws, size_t ws_size,
                              hipStream_t stream){
    const float* q = (const float*)d_in[0];
    const float* k = (const float*)d_in[1];
    const float* v = (const float*)d_in[2];
    float* out = (float*)d_out;

    short* kb  = (short*)d_ws;                 // 4,194,304 bf16 = 8 MiB
    short* vtp = (short*)d_ws + 4194304;       // 4,194,304 bf16 = 8 MiB

    cast_k_bf16<<<2048, 256, 0, stream>>>(k, kb);
    transpose_v<<<dim3(SK_ / 64, D_ / 32, B_ * HKV_), 256, 0, stream>>>(v, vtp);
    attn_kernel<<<B_ * HKV_ * (SQ_ / QBLK), 256, 0, stream>>>(q, kb, vtp, out);
}